// Round 2
// baseline (74.462 us; speedup 1.0000x reference)
//
#include <hip/hip_runtime.h>

// SymmetricPooling: depthwise 5x5 binary-symmetric conv, VALID, stride 1.
// x: (16,128,128,32) f32 -> out: (16,124,124,288) f32, channel order c*9+f,
// f = eta*3 + phi, taps = {eta,4-eta} x {phi,4-phi} (deduped at centre).
//
// R2: slide the 5-row window down y in registers (31-row strips). Loads drop
// from 25/row to 5/row (+4 warmup rows amortized). Full unroll -> window
// rotation is register renaming, not moves. Double-buffered LDS store tile ->
// one __syncthreads per row.

#define BB 16
#define HH 128
#define WW 128
#define CC 32
#define OH 124
#define OW 124
#define NF 9
#define OC (CC * NF)   // 288
#define TX 4           // x positions per block
#define NXB (OW / TX)  // 31
#define YS 31          // output rows per block
#define NYS (OH / YS)  // 4

__global__ __launch_bounds__(128)
void sympool_kernel(const float* __restrict__ x, float* __restrict__ out) {
    __shared__ float tile[2][TX * OC];  // 2 x 4.5 KB

    const int t = threadIdx.x;
    const int c = t & 31;        // channel
    const int d = t >> 5;        // 0..3, x offset within tile

    const int blk  = blockIdx.x;
    const int xb   = blk % NXB;
    const int rest = blk / NXB;
    const int ys   = rest % NYS;
    const int b    = rest / NYS;
    const int x0   = xb * TX;
    const int xx   = x0 + d;
    const int y0   = ys * YS;

    // Per-lane base: lanes 0..31 = channels (128B), lanes 32..63 = next x
    // -> each global_load_dword is one contiguous 256B wave transaction.
    const float* p = x + ((size_t)((b * HH + y0) * WW + xx)) * CC + c;

    // Warm-up: input rows y0..y0+3 into the rotating window.
    float v[5][5];
#pragma unroll
    for (int i = 0; i < 4; ++i)
#pragma unroll
        for (int j = 0; j < 5; ++j)
            v[i][j] = p[(i * WW + j) * CC];

    const float* prow = p + 4 * (WW * CC);          // input row y0+s+4
    float*       orow = out + ((size_t)((b * OH + y0) * OW + x0)) * OC;

#pragma unroll
    for (int s = 0; s < YS; ++s) {
        // rotating indices (compile-time after full unroll -> no v_movs)
        const int i0 = (s + 0) % 5, i1 = (s + 1) % 5, i2 = (s + 2) % 5,
                  i3 = (s + 3) % 5, i4 = (s + 4) % 5;

        // load bottom row (input y0+s+4), cols xx..xx+4
#pragma unroll
        for (int j = 0; j < 5; ++j) v[i4][j] = prow[j * CC];
        prow += WW * CC;

        // row-pair sums then column-pair sums -> 9 outputs (16 adds)
        float* dst = &tile[s & 1][d * OC + c * NF];
        float R0[5], R1[5];
#pragma unroll
        for (int j = 0; j < 5; ++j) {
            R0[j] = v[i0][j] + v[i4][j];
            R1[j] = v[i1][j] + v[i3][j];
        }
        dst[0] = R0[0] + R0[4];
        dst[1] = R0[1] + R0[3];
        dst[2] = R0[2];
        dst[3] = R1[0] + R1[4];
        dst[4] = R1[1] + R1[3];
        dst[5] = R1[2];
        dst[6] = v[i2][0] + v[i2][4];
        dst[7] = v[i2][1] + v[i2][3];
        dst[8] = v[i2][2];

        __syncthreads();  // also covers reuse of tile[s&1] two iters later

        // coalesced float4 stream-out of the 4x288 tile (one output row seg)
        const float4* tv   = (const float4*)tile[s & 1];
        float4*       outv = (float4*)orow;
#pragma unroll
        for (int k = 0; k < 3; ++k) {
            int idx = t + k * 128;
            if (idx < TX * OC / 4) outv[idx] = tv[idx];
        }
        orow += (size_t)OW * OC;
    }
}

extern "C" void kernel_launch(void* const* d_in, const int* in_sizes, int n_in,
                              void* d_out, int out_size, void* d_ws, size_t ws_size,
                              hipStream_t stream) {
    const float* x = (const float*)d_in[0];
    // d_in[1] is the binary symmetric kernel; its structure is hardcoded.
    float* out = (float*)d_out;

    const int grid = BB * NYS * NXB;  // 16*4*31 = 1984
    sympool_kernel<<<grid, 128, 0, stream>>>(x, out);
}